// Round 9
// baseline (1278.794 us; speedup 1.0000x reference)
//
#include <hip/hip_runtime.h>

#define NB 128
#define CL 256
#define EE 512
#define AA 128
#define LL 64
#define HH 8
#define HD 64
#define NSTEPS 20
#define BLROWS (NB*LL)   // 8192
#define LOG2E 1.4426950408889634f
// Q pre-scale: keeps fp8 Q out of e4m3 subnormals; removed via 1/64 in exp2 arg
#define QSCALE 64.0f
#define INV_QS 0.015625f

typedef __attribute__((ext_vector_type(8))) short bf16x8;
typedef __attribute__((ext_vector_type(4))) float f32x4;
typedef unsigned int u32;

union F8 { u32 u[2]; long l; };   // 8-byte fp8 MFMA operand (2 VGPRs)

__device__ __forceinline__ unsigned short f2bf(float f) {
    union { float f; unsigned u; } x; x.f = f;
    unsigned u = x.u;
    u += 0x7fffu + ((u >> 16) & 1u);   // round-to-nearest-even
    return (unsigned short)(u >> 16);
}
// pack f32x4 -> 4 x fp8 e4m3 (OCP on gfx950)
__device__ __forceinline__ u32 pk4f8(f32x4 v) {
    u32 r = __builtin_amdgcn_cvt_pk_fp8_f32(v[0], v[1], 0, false);
    r = __builtin_amdgcn_cvt_pk_fp8_f32(v[2], v[3], r, true);
    return r;
}
__device__ __forceinline__ unsigned char f2f8(float v) {
    return (unsigned char)(__builtin_amdgcn_cvt_pk_fp8_f32(v, v, 0, false) & 0xffu);
}

// async global->LDS, 16B per lane
__device__ __forceinline__ void async_copy16(const unsigned short* g, unsigned short* l) {
    __builtin_amdgcn_global_load_lds((const __attribute__((address_space(1))) u32*)g,
                                     (__attribute__((address_space(3))) u32*)l, 16, 0, 0);
}

#define MFMA(a,b,c)  __builtin_amdgcn_mfma_f32_16x16x32_bf16(a, b, c, 0, 0, 0)
#define MFMA8(a,b,c) __builtin_amdgcn_mfma_f32_16x16x32_fp8_fp8(a, b, c, 0, 0, 0)

// D-layout u32-packed quads -> A/B-operand 8-byte frag (verified rounds 4-7)
__device__ __forceinline__ F8 build8(const u32* p, int kk, int srcA, int srcB, int odd) {
    u32 a0 = __shfl((int)p[2*kk],   srcA, 64);
    u32 b0 = __shfl((int)p[2*kk+1], srcA, 64);
    u32 a1 = __shfl((int)p[2*kk],   srcB, 64);
    u32 b1 = __shfl((int)p[2*kk+1], srcB, 64);
    F8 f; f.u[0] = odd ? b0 : a0; f.u[1] = odd ? b1 : a1;
    return f;
}

// ---------------- prep kernels ----------------

__global__ void cvt8_kernel(const float* __restrict__ src, unsigned short* __restrict__ dst, int n8) {
    int i = blockIdx.x*256 + threadIdx.x;
    if (i >= n8) return;
    const float* s = src + (size_t)i*8;
    f32x4 v0 = *(const f32x4*)s;
    f32x4 v1 = *(const f32x4*)(s + 4);
    bf16x8 o;
    o[0]=(short)f2bf(v0[0]); o[1]=(short)f2bf(v0[1]);
    o[2]=(short)f2bf(v0[2]); o[3]=(short)f2bf(v0[3]);
    o[4]=(short)f2bf(v1[0]); o[5]=(short)f2bf(v1[1]);
    o[6]=(short)f2bf(v1[2]); o[7]=(short)f2bf(v1[3]);
    *(bf16x8*)(dst + (size_t)i*8) = o;
}

// Wq_eff = (0.125*log2e*QSCALE)*(in_w[:E] @ qp_w); Wo_eff = outp_w @ op_w; bo_eff
__global__ void prep_eff_kernel(const float* __restrict__ in_w, const float* __restrict__ qp_w,
                                const float* __restrict__ outp_w, const float* __restrict__ op_w,
                                const float* __restrict__ op_b, const float* __restrict__ outp_b,
                                unsigned short* __restrict__ wq, unsigned short* __restrict__ wo,
                                float* __restrict__ bo) {
    int tid = blockIdx.x*256 + threadIdx.x;
    if (tid < 65536) {
        int n = tid >> 7, k = tid & 127;
        float s = 0.f;
        for (int e = 0; e < 512; ++e) s += in_w[(size_t)n*512 + e] * qp_w[(size_t)e*128 + k];
        wq[(size_t)n*128 + k] = f2bf(s * (0.125f * LOG2E * QSCALE));
    } else if (tid < 131072) {
        int t2 = tid - 65536; int n = t2 >> 9, k = t2 & 511;
        float s = 0.f;
        for (int e = 0; e < 512; ++e) s += outp_w[(size_t)n*512 + e] * op_w[(size_t)e*512 + k];
        wo[(size_t)n*512 + k] = f2bf(s);
    } else if (tid < 131200) {
        int n = tid - 131072;
        float s = outp_b[n];
        for (int e = 0; e < 512; ++e) s += outp_w[(size_t)n*512 + e] * op_b[e];
        bo[n] = s;
    }
}

__global__ void temb_kernel(const float* __restrict__ t1_w, const float* __restrict__ t1_b,
                            const float* __restrict__ t2_w, const float* __restrict__ t2_b,
                            float* __restrict__ temb) {
    int tid = blockIdx.x*256 + threadIdx.x;
    if (tid >= NSTEPS*512) return;
    int s = tid >> 9, e = tid & 511;
    float t = 1.0f - 0.05f * (float)s;
    float acc = t2_b[e];
    for (int i = 0; i < 512; ++i)
        acc += t2_w[(size_t)e*512 + i] * fmaxf(t * t1_w[i] + t1_b[i], 0.f);
    temb[tid] = acc;
}

__global__ void qbias_kernel(const float* __restrict__ in_w, const float* __restrict__ in_b,
                             const float* __restrict__ qp_b, const float* __restrict__ temb,
                             float* __restrict__ qbias) {
    int tid = blockIdx.x*256 + threadIdx.x;
    if (tid >= NSTEPS*512) return;
    int s = tid >> 9, n = tid & 511;
    float acc = in_b[n];
    const float* te = temb + (size_t)s*512;
    for (int e = 0; e < 512; ++e)
        acc += in_w[(size_t)n*512 + e] * (qp_b[e] + te[e]);
    qbias[tid] = acc * (0.125f * LOG2E * QSCALE);
}

// ---------------- fused K+V projection GEMM -> fp8 K/V (unchanged) --------
__global__ __launch_bounds__(512, 8) void kv_kernel(const unsigned short* __restrict__ condb,
                                                    const unsigned short* __restrict__ wkv,
                                                    const float* __restrict__ bias,
                                                    unsigned char* __restrict__ K8,
                                                    unsigned char* __restrict__ V8) {
    __shared__ unsigned short As[128*64];
    __shared__ unsigned short Bs[128*64];
    int tid = threadIdx.x;
    int blk = blockIdx.x;
    int xcd = blk & 7, j = blk >> 3;
    int m0 = (xcd*32 + (j >> 3)) * 128;
    int n0 = (j & 7) * 128;
    int wv = tid >> 6, lane = tid & 63, r = lane & 15, q = lane >> 4;
    int srow = lane >> 3;
    int sg = (lane & 7) ^ srow;
    const unsigned short* agl = condb + (size_t)(m0 + wv*16 + srow)*512 + sg*8;
    const unsigned short* bgl = wkv   + (size_t)(n0 + wv*16 + srow)*512 + sg*8;
    f32x4 acc[8] = {};
#pragma unroll
    for (int kt = 0; kt < 8; ++kt) {
        int k0 = kt * 64;
#pragma unroll
        for (int ii = 0; ii < 2; ++ii) {
            async_copy16(agl + (size_t)(ii*8)*512 + k0, &As[(wv*16 + ii*8)*64]);
            async_copy16(bgl + (size_t)(ii*8)*512 + k0, &Bs[(wv*16 + ii*8)*64]);
        }
        __syncthreads();
#pragma unroll
        for (int kk = 0; kk < 2; ++kk) {
            int gof = ((kk*4 + q) ^ (r & 7)) * 8;
            bf16x8 a = *(const bf16x8*)&As[(wv*16 + r)*64 + gof];
#pragma unroll
            for (int t = 0; t < 8; ++t) {
                bf16x8 b = *(const bf16x8*)&Bs[(t*16 + r)*64 + gof];
                acc[t] = MFMA(a, b, acc[t]);
            }
        }
        __syncthreads();
    }
    int mbase = m0 + wv*16 + q*4;
    int bb = mbase >> 8, kpb = mbase & 255;
#pragma unroll
    for (int t = 0; t < 8; ++t) {
        int n = n0 + t*16 + r;
        float bs = bias[n];
        if (n < 512) {
            int h = n >> 6, d = n & 63;
            int colp = ((d>>3)&3)*16 + ((d>>5)&1)*8 + (d&7);
            unsigned char* kp = K8 + (size_t)(bb*HH + h)*16384 + colp;
#pragma unroll
            for (int i = 0; i < 4; ++i)
                kp[(kpb + i)*64] = f2f8(acc[t][i] + bs);
        } else {
            int n2 = n - 512, h = n2 >> 6, d = n2 & 63;
            int kk = kpb >> 5, qq = (kpb >> 3) & 3, jb = kpb & 7;
            int colv = (kk>>1)*64 + qq*16 + (kk&1)*8 + jb;
            u32 w01 = __builtin_amdgcn_cvt_pk_fp8_f32(acc[t][0]+bs, acc[t][1]+bs, 0, false);
            w01 = __builtin_amdgcn_cvt_pk_fp8_f32(acc[t][2]+bs, acc[t][3]+bs, w01, true);
            *(u32*)(V8 + (size_t)(bb*HH + h)*16384 + d*256 + colv) = w01;
        }
    }
}

// ---------------- mega kernel: all 20 steps --------------------------------
// 256 blocks (1/CU) x 8 waves; wave = head, both 16-row q-tiles batched.
// FLASH over FOUR 64-key quarters (r6 used 2x128 halves and spilled 141MB:
// arch live ~130 > 128-arch half of the 256-reg/wave budget at 8 waves).
// Quarters shrink kbuf/vbuf to 4 uint4 (16 regs) each, pp to 4+4 -> arch
// live ~90 < 128: spill-free (r8 proved the write-size counter validates
// this) AND 2 waves/SIMD (vs r8's 1) to cover shuffle/exp2/L2 latency.
__global__ __launch_bounds__(512, 2) void mega_kernel(
        const unsigned char* __restrict__ Kg,    // [b*8+h][256][64] fp8, col-permuted
        const unsigned char* __restrict__ Vg,    // [b*8+h][64][256] fp8, col-permuted
        const float* __restrict__ noise,
        const unsigned short* __restrict__ wq,   // [512][128] bf16 (x64*log2e scale)
        const float* __restrict__ qbiasB,        // [20][512]
        const unsigned short* __restrict__ wo,   // [128][512]
        const float* __restrict__ bo,
        const float* __restrict__ ln_g, const float* __restrict__ ln_b,
        const unsigned short* __restrict__ f1w,  // [512][128]
        const float* __restrict__ f1_b,
        const unsigned short* __restrict__ f2w,  // [128][512]
        const float* __restrict__ f2_b,
        float* __restrict__ outp) {
    __shared__ unsigned short xS[32*136];     // 8.7 KB
    __shared__ unsigned short cuS[32*520];    // 33.3 KB: ctx, then full-width u
    __shared__ unsigned short hnS[32*136];    // 8.7 KB
    __shared__ float redS[32*4], redS2[32*4];

    int tid = threadIdx.x, w = tid >> 6, lane = tid & 63, r = lane & 15, q = lane >> 4;
    int vblk = ((blockIdx.x & 7) << 5) | (blockIdx.x >> 3);   // same-b pairs on one XCD
    int b = vblk >> 1;
    int row0 = vblk * 32;
    int h = w;                            // phase A: one head per wave
    int tB = w & 1, cg = w >> 1;          // phase B: row-tile, col-group (cols cg*32)
    int srcA = r + ((2*q) & 3)*16;
    int srcB = r + ((2*q + 1) & 3)*16;
    int odd = (q >> 1) & 1;

    float xf[2][4];
#pragma unroll
    for (int t = 0; t < 2; ++t)
#pragma unroll
        for (int i = 0; i < 4; ++i) {
            int rl = tB*16 + q*4 + i, col = cg*32 + t*16 + r;
            float v = noise[(size_t)(row0 + rl)*AA + col];
            xf[t][i] = v;
            xS[rl*136 + col] = f2bf(v);
        }

    size_t bh = (size_t)b*HH + h;
    const unsigned char* kbase = Kg + bh*16384;
    const unsigned char* vbase = Vg + bh*16384;
    __syncthreads();

    const float dt = -1.f / (float)NSTEPS;

#pragma unroll 1
    for (int s = 0; s < NSTEPS; ++s) {
        const float* qb_s = qbiasB + (size_t)s*512;

        // ===== Phase A: head h, both q-tiles, flash over 4 key-quarters =====
        {
            // Q-proj (bf16) both tiles: a = wq rows (L2-hot), shared
            f32x4 qacc0[4] = {}, qacc1[4] = {};
#pragma unroll
            for (int kk = 0; kk < 4; ++kk) {
                bf16x8 bx0 = *(const bf16x8*)&xS[(r)*136 + kk*32 + q*8];
                bf16x8 bx1 = *(const bf16x8*)&xS[(16 + r)*136 + kk*32 + q*8];
#pragma unroll
                for (int t = 0; t < 4; ++t) {
                    bf16x8 a = *(const bf16x8*)(wq + (size_t)(h*HD + t*16 + r)*AA + kk*32 + q*8);
                    qacc0[t] = MFMA(a, bx0, qacc0[t]);
                    qacc1[t] = MFMA(a, bx1, qacc1[t]);
                }
            }
            u32 qp0[4], qp1[4];
#pragma unroll
            for (int t = 0; t < 4; ++t) {
                f32x4 qb4 = *(const f32x4*)(qb_s + h*HD + t*16 + q*4);
                f32x4 v0, v1;
#pragma unroll
                for (int i = 0; i < 4; ++i) { v0[i] = qacc0[t][i] + qb4[i]; v1[i] = qacc1[t][i] + qb4[i]; }
                qp0[t] = pk4f8(v0);
                qp1[t] = pk4f8(v1);
            }
            F8 bq0[2], bq1[2];
            bq0[0] = build8(qp0, 0, srcA, srcB, odd);
            bq0[1] = build8(qp0, 1, srcA, srcB, odd);
            bq1[0] = build8(qp1, 0, srcA, srcB, odd);
            bq1[1] = build8(qp1, 1, srcA, srcB, odd);

            // flash state: running max (scaled units) + running sum per tile
            float m0r = -3e38f, m1r = -3e38f;
            float l0 = 0.f, l1 = 0.f;
            f32x4 c0[4] = {}, c1[4] = {};

#pragma unroll
            for (int qq = 0; qq < 4; ++qq) {
                // K prefetch for this quarter (4 x 16B)
                uint4 kbuf[4];
#pragma unroll
                for (int t = 0; t < 4; ++t)
                    kbuf[t] = *(const uint4*)(kbase + (size_t)((qq*4 + t)*16 + r)*64 + q*16);

                // S^T fp8 both tiles for this quarter
                f32x4 s0[4] = {}, s1[4] = {};
#pragma unroll
                for (int t = 0; t < 4; ++t) {
                    F8 k0, k1;
                    k0.u[0] = kbuf[t].x; k0.u[1] = kbuf[t].y;
                    k1.u[0] = kbuf[t].z; k1.u[1] = kbuf[t].w;
                    s0[t] = MFMA8(k0.l, bq0[0].l, s0[t]);
                    s0[t] = MFMA8(k1.l, bq0[1].l, s0[t]);
                    s1[t] = MFMA8(k0.l, bq1[0].l, s1[t]);
                    s1[t] = MFMA8(k1.l, bq1[1].l, s1[t]);
                }

                // V prefetch for this quarter (independent of softmax VALU)
                uint4 vbuf[4];
#pragma unroll
                for (int t = 0; t < 4; ++t)
                    vbuf[t] = *(const uint4*)(vbase + (size_t)(t*16 + r)*256 + qq*64 + q*16);

                // quarter max (4-way split chains), tile0 and tile1
                float a0 = s0[0][0], a1 = s0[0][1], a2 = s0[0][2], a3 = s0[0][3];
                float b0 = s1[0][0], b1 = s1[0][1], b2 = s1[0][2], b3 = s1[0][3];
#pragma unroll
                for (int t = 1; t < 4; ++t) {
                    a0 = fmaxf(a0, s0[t][0]); a1 = fmaxf(a1, s0[t][1]);
                    a2 = fmaxf(a2, s0[t][2]); a3 = fmaxf(a3, s0[t][3]);
                    b0 = fmaxf(b0, s1[t][0]); b1 = fmaxf(b1, s1[t][1]);
                    b2 = fmaxf(b2, s1[t][2]); b3 = fmaxf(b3, s1[t][3]);
                }
                float hm0 = fmaxf(fmaxf(a0, a1), fmaxf(a2, a3));
                float hm1 = fmaxf(fmaxf(b0, b1), fmaxf(b2, b3));
                hm0 = fmaxf(hm0, __shfl_xor(hm0, 16));
                hm0 = fmaxf(hm0, __shfl_xor(hm0, 32));
                hm1 = fmaxf(hm1, __shfl_xor(hm1, 16));
                hm1 = fmaxf(hm1, __shfl_xor(hm1, 32));
                float nm0 = fmaxf(m0r, hm0 * INV_QS);
                float nm1 = fmaxf(m1r, hm1 * INV_QS);
                float rs0 = exp2f(m0r - nm0);   // <=1; 0 on first quarter
                float rs1 = exp2f(m1r - nm1);
                m0r = nm0; m1r = nm1;

                // exp + sum + pack (no writeback into s)
                u32 pp0[4], pp1[4];
                float t00 = 0.f, t01 = 0.f, t10 = 0.f, t11 = 0.f;
#pragma unroll
                for (int t = 0; t < 4; ++t) {
                    float e0 = exp2f(fmaf(s0[t][0], INV_QS, -nm0));
                    float e1 = exp2f(fmaf(s0[t][1], INV_QS, -nm0));
                    float e2 = exp2f(fmaf(s0[t][2], INV_QS, -nm0));
                    float e3 = exp2f(fmaf(s0[t][3], INV_QS, -nm0));
                    t00 += e0 + e2; t01 += e1 + e3;
                    f32x4 w0; w0[0]=e0*QSCALE; w0[1]=e1*QSCALE; w0[2]=e2*QSCALE; w0[3]=e3*QSCALE;
                    pp0[t] = pk4f8(w0);
                    float f0 = exp2f(fmaf(s1[t][0], INV_QS, -nm1));
                    float f1 = exp2f(fmaf(s1[t][1], INV_QS, -nm1));
                    float f2 = exp2f(fmaf(s1[t][2], INV_QS, -nm1));
                    float f3 = exp2f(fmaf(s1[t][3], INV_QS, -nm1));
                    t10 += f0 + f2; t11 += f1 + f3;
                    f32x4 w1; w1[0]=f0*QSCALE; w1[1]=f1*QSCALE; w1[2]=f2*QSCALE; w1[3]=f3*QSCALE;
                    pp1[t] = pk4f8(w1);
                }
                l0 = l0 * rs0 + (t00 + t01);
                l1 = l1 * rs1 + (t10 + t11);

                // rescale ctx accumulators by row-redistributed factors
                float rr0[4], rr1[4];
#pragma unroll
                for (int i = 0; i < 4; ++i) {
                    rr0[i] = __shfl(rs0, q*4 + i);
                    rr1[i] = __shfl(rs1, q*4 + i);
                }
#pragma unroll
                for (int t = 0; t < 4; ++t)
#pragma unroll
                    for (int i = 0; i < 4; ++i) {
                        c0[t][i] *= rr0[i];
                        c1[t][i] *= rr1[i];
                    }

                // PV fp8 for this quarter (one 64-key group)
                {
                    F8 a00 = build8(pp0, 0, srcA, srcB, odd);
                    F8 a01 = build8(pp0, 1, srcA, srcB, odd);
                    F8 a10 = build8(pp1, 0, srcA, srcB, odd);
                    F8 a11 = build8(pp1, 1, srcA, srcB, odd);
#pragma unroll
                    for (int t = 0; t < 4; ++t) {
                        F8 v0, v1;
                        v0.u[0] = vbuf[t].x; v0.u[1] = vbuf[t].y;
                        v1.u[0] = vbuf[t].z; v1.u[1] = vbuf[t].w;
                        c0[t] = MFMA8(a00.l, v0.l, c0[t]);
                        c0[t] = MFMA8(a01.l, v1.l, c0[t]);
                        c1[t] = MFMA8(a10.l, v0.l, c1[t]);
                        c1[t] = MFMA8(a11.l, v1.l, c1[t]);
                    }
                }
            }

            // final normalization: reduce l across the 4 lanes of each row
            l0 += __shfl_xor(l0, 16); l0 += __shfl_xor(l0, 32);
            l1 += __shfl_xor(l1, 16); l1 += __shfl_xor(l1, 32);
            float iv0 = 1.0f / l0, iv1 = 1.0f / l1;
            float sc0[4], sc1[4];
#pragma unroll
            for (int i = 0; i < 4; ++i) {
                sc0[i] = INV_QS * __shfl(iv0, q*4 + i);
                sc1[i] = INV_QS * __shfl(iv1, q*4 + i);
            }
#pragma unroll
            for (int t = 0; t < 4; ++t)
#pragma unroll
                for (int i = 0; i < 4; ++i) {
                    cuS[(q*4 + i)*520 + h*HD + t*16 + r]      = f2bf(c0[t][i] * sc0[i]);
                    cuS[(16 + q*4 + i)*520 + h*HD + t*16 + r] = f2bf(c1[t][i] * sc1[i]);
                }
        }
        __syncthreads();   // ctx complete

        // ===== Phase B: out-proj + residual + LayerNorm =====
        f32x4 oacc[2] = {};
#pragma unroll
        for (int kk = 0; kk < 16; ++kk) {
            bf16x8 a = *(const bf16x8*)&cuS[(tB*16 + r)*520 + kk*32 + q*8];
#pragma unroll
            for (int t = 0; t < 2; ++t) {
                bf16x8 bw = *(const bf16x8*)(wo + (size_t)(cg*32 + t*16 + r)*EE + kk*32 + q*8);
                oacc[t] = MFMA(a, bw, oacc[t]);
            }
        }
        float hv[2][4];
#pragma unroll
        for (int t = 0; t < 2; ++t) {
            float bov = bo[cg*32 + t*16 + r];
#pragma unroll
            for (int i = 0; i < 4; ++i) hv[t][i] = oacc[t][i] + bov + xf[t][i];
        }
#pragma unroll
        for (int i = 0; i < 4; ++i) {
            float s1 = hv[0][i] + hv[1][i];
            float s2 = hv[0][i]*hv[0][i] + hv[1][i]*hv[1][i];
            s1 += __shfl_xor(s1, 1);  s2 += __shfl_xor(s2, 1);
            s1 += __shfl_xor(s1, 2);  s2 += __shfl_xor(s2, 2);
            s1 += __shfl_xor(s1, 4);  s2 += __shfl_xor(s2, 4);
            s1 += __shfl_xor(s1, 8);  s2 += __shfl_xor(s2, 8);
            if (r == 0) { redS[(tB*16 + q*4 + i)*4 + cg] = s1; redS2[(tB*16 + q*4 + i)*4 + cg] = s2; }
        }
        __syncthreads();   // also: all ctx reads from cuS are done after this
        float hnv[2][4];
#pragma unroll
        for (int i = 0; i < 4; ++i) {
            int row = tB*16 + q*4 + i;
            float s1 = redS [row*4+0] + redS [row*4+1] + redS [row*4+2] + redS [row*4+3];
            float s2 = redS2[row*4+0] + redS2[row*4+1] + redS2[row*4+2] + redS2[row*4+3];
            float mu = s1 * (1.f/128.f);
            float var = s2 * (1.f/128.f) - mu*mu;
            float rstd = rsqrtf(var + 1e-5f);
#pragma unroll
            for (int t = 0; t < 2; ++t) {
                int col = cg*32 + t*16 + r;
                float v = (hv[t][i] - mu) * rstd * ln_g[col] + ln_b[col];
                hnv[t][i] = v;
                hnS[row*136 + col] = f2bf(v);
            }
        }
        __syncthreads();

        // ===== FFN: full-width u into cuS, single barrier =====
        f32x4 o2[2] = {};
#pragma unroll 1
        for (int nt = 0; nt < 4; ++nt) {
            f32x4 a1[2] = {};
#pragma unroll
            for (int kk = 0; kk < 4; ++kk) {
                bf16x8 a = *(const bf16x8*)&hnS[(tB*16 + r)*136 + kk*32 + q*8];
#pragma unroll
                for (int t = 0; t < 2; ++t) {
                    bf16x8 bw = *(const bf16x8*)(f1w + (size_t)(nt*128 + cg*32 + t*16 + r)*AA + kk*32 + q*8);
                    a1[t] = MFMA(a, bw, a1[t]);
                }
            }
#pragma unroll
            for (int t = 0; t < 2; ++t) {
                float b1 = f1_b[nt*128 + cg*32 + t*16 + r];
#pragma unroll
                for (int i = 0; i < 4; ++i)
                    cuS[(tB*16 + q*4 + i)*520 + nt*128 + cg*32 + t*16 + r] = f2bf(fmaxf(a1[t][i] + b1, 0.f));
            }
        }
        __syncthreads();   // all of u visible to all waves
#pragma unroll 1
        for (int nt = 0; nt < 4; ++nt) {
#pragma unroll
            for (int kk = 0; kk < 4; ++kk) {
                bf16x8 a = *(const bf16x8*)&cuS[(tB*16 + r)*520 + nt*128 + kk*32 + q*8];
#pragma unroll
                for (int t = 0; t < 2; ++t) {
                    bf16x8 bw = *(const bf16x8*)(f2w + (size_t)(cg*32 + t*16 + r)*EE + nt*128 + kk*32 + q*8);
                    o2[t] = MFMA(a, bw, o2[t]);
                }
            }
        }

        // ===== x update =====
        if (s < NSTEPS - 1) {
#pragma unroll
            for (int t = 0; t < 2; ++t) {
                float b2 = f2_b[cg*32 + t*16 + r];
#pragma unroll
                for (int i = 0; i < 4; ++i) {
                    float outv = hnv[t][i] + o2[t][i] + b2;
                    float xn = xf[t][i] + dt * outv;
                    xf[t][i] = xn;
                    xS[(tB*16 + q*4 + i)*136 + cg*32 + t*16 + r] = f2bf(xn);
                }
            }
            __syncthreads();   // xS ready; cuS (u) reads done -> reusable as ctx
        } else {
#pragma unroll
            for (int t = 0; t < 2; ++t) {
                float b2 = f2_b[cg*32 + t*16 + r];
#pragma unroll
                for (int i = 0; i < 4; ++i) {
                    float outv = hnv[t][i] + o2[t][i] + b2;
                    outp[(size_t)(row0 + tB*16 + q*4 + i)*AA + cg*32 + t*16 + r] = xf[t][i] + dt * outv;
                }
            }
        }
    }
}

extern "C" void kernel_launch(void* const* d_in, const int* in_sizes, int n_in,
                              void* d_out, int out_size, void* d_ws, size_t ws_size,
                              hipStream_t stream) {
    const float* cond   = (const float*)d_in[0];
    const float* noise  = (const float*)d_in[1];
    const float* t1_w   = (const float*)d_in[2];
    const float* t1_b   = (const float*)d_in[3];
    const float* t2_w   = (const float*)d_in[4];
    const float* t2_b   = (const float*)d_in[5];
    const float* qp_w   = (const float*)d_in[6];
    const float* qp_b   = (const float*)d_in[7];
    const float* in_w   = (const float*)d_in[8];
    const float* in_b   = (const float*)d_in[9];
    const float* op_w   = (const float*)d_in[10];
    const float* op_b   = (const float*)d_in[11];
    const float* outp_w = (const float*)d_in[12];
    const float* outp_b = (const float*)d_in[13];
    const float* f1_w   = (const float*)d_in[14];
    const float* f1_b   = (const float*)d_in[15];
    const float* f2_w   = (const float*)d_in[16];
    const float* f2_b   = (const float*)d_in[17];
    const float* ln_g   = (const float*)d_in[18];
    const float* ln_bp  = (const float*)d_in[19];

    char* w = (char*)d_ws;
    auto alloc = [&](size_t bytes) {
        char* p = w;
        w += (bytes + 255) & ~(size_t)255;
        return p;
    };
    unsigned char*  K8     = (unsigned char*)alloc((size_t)NB*HH*CL*HD);      // 16.8 MB fp8
    unsigned char*  V8     = (unsigned char*)alloc((size_t)NB*HH*HD*CL);      // 16.8 MB fp8
    unsigned short* condb  = (unsigned short*)alloc((size_t)NB*CL*EE*2);      // 33.5 MB
    unsigned short* wkv_bf = (unsigned short*)alloc((size_t)1024*512*2);      // 1 MB
    unsigned short* wq_bf  = (unsigned short*)alloc((size_t)512*128*2);
    unsigned short* wo_bf  = (unsigned short*)alloc((size_t)128*512*2);
    unsigned short* f1_bf  = (unsigned short*)alloc((size_t)512*128*2);
    unsigned short* f2_bf  = (unsigned short*)alloc((size_t)128*512*2);
    float*          bo_eff = (float*)alloc(128*4);
    float*          tembB  = (float*)alloc((size_t)NSTEPS*512*4);
    float*          qbiasB = (float*)alloc((size_t)NSTEPS*512*4);
    (void)ws_size; (void)n_in; (void)in_sizes; (void)out_size;

    // --- one-time prep ---
    cvt8_kernel<<<8192, 256, 0, stream>>>(cond, condb, NB*CL*EE/8);
    cvt8_kernel<<<256, 256, 0, stream>>>(in_w + 512*512, wkv_bf, 1024*512/8);
    cvt8_kernel<<<32, 256, 0, stream>>>(f1_w, f1_bf, 512*128/8);
    cvt8_kernel<<<32, 256, 0, stream>>>(f2_w, f2_bf, 128*512/8);
    prep_eff_kernel<<<513, 256, 0, stream>>>(in_w, qp_w, outp_w, op_w, op_b, outp_b,
                                             wq_bf, wo_bf, bo_eff);
    temb_kernel<<<40, 256, 0, stream>>>(t1_w, t1_b, t2_w, t2_b, tembB);
    qbias_kernel<<<40, 256, 0, stream>>>(in_w, in_b, qp_b, tembB, qbiasB);
    kv_kernel<<<2048, 512, 0, stream>>>(condb, wkv_bf, in_b + 512, K8, V8);

    // --- all 20 denoise steps, one kernel, 256 blocks x 8 waves ---
    mega_kernel<<<256, 512, 0, stream>>>(K8, V8, noise, wq_bf, qbiasB,
                                         wo_bf, bo_eff, ln_g, ln_bp,
                                         f1_bf, f1_b, f2_bf, f2_b,
                                         (float*)d_out);
}

// Round 14
// 1109.308 us; speedup vs baseline: 1.1528x; 1.1528x over previous
//
#include <hip/hip_runtime.h>

#define NB 128
#define CL 256
#define EE 512
#define AA 128
#define LL 64
#define HH 8
#define HD 64
#define NSTEPS 20
#define BLROWS (NB*LL)   // 8192
#define LOG2E 1.4426950408889634f
// Q pre-scale: keeps fp8 Q out of e4m3 subnormals; removed via 1/64 in exp2 arg
#define QSCALE 64.0f
#define INV_QS 0.015625f

typedef __attribute__((ext_vector_type(8))) short bf16x8;
typedef __attribute__((ext_vector_type(4))) float f32x4;
typedef unsigned int u32;

union F8 { u32 u[2]; long l; };   // 8-byte fp8 MFMA operand (2 VGPRs)

__device__ __forceinline__ unsigned short f2bf(float f) {
    union { float f; unsigned u; } x; x.f = f;
    unsigned u = x.u;
    u += 0x7fffu + ((u >> 16) & 1u);   // round-to-nearest-even
    return (unsigned short)(u >> 16);
}
// pack f32x4 -> 4 x fp8 e4m3 (OCP on gfx950)
__device__ __forceinline__ u32 pk4f8(f32x4 v) {
    u32 r = __builtin_amdgcn_cvt_pk_fp8_f32(v[0], v[1], 0, false);
    r = __builtin_amdgcn_cvt_pk_fp8_f32(v[2], v[3], r, true);
    return r;
}
__device__ __forceinline__ unsigned char f2f8(float v) {
    return (unsigned char)(__builtin_amdgcn_cvt_pk_fp8_f32(v, v, 0, false) & 0xffu);
}

// async global->LDS, 16B per lane
__device__ __forceinline__ void async_copy16(const unsigned short* g, unsigned short* l) {
    __builtin_amdgcn_global_load_lds((const __attribute__((address_space(1))) u32*)g,
                                     (__attribute__((address_space(3))) u32*)l, 16, 0, 0);
}

#define MFMA(a,b,c)  __builtin_amdgcn_mfma_f32_16x16x32_bf16(a, b, c, 0, 0, 0)
#define MFMA8(a,b,c) __builtin_amdgcn_mfma_f32_16x16x32_fp8_fp8(a, b, c, 0, 0, 0)

// D-layout u32-packed quads -> A/B-operand 8-byte frag (verified rounds 4-7)
__device__ __forceinline__ F8 build8(const u32* p, int kk, int srcA, int srcB, int odd) {
    u32 a0 = __shfl((int)p[2*kk],   srcA, 64);
    u32 b0 = __shfl((int)p[2*kk+1], srcA, 64);
    u32 a1 = __shfl((int)p[2*kk],   srcB, 64);
    u32 b1 = __shfl((int)p[2*kk+1], srcB, 64);
    F8 f; f.u[0] = odd ? b0 : a0; f.u[1] = odd ? b1 : a1;
    return f;
}

// ---------------- prep kernels ----------------

__global__ void cvt8_kernel(const float* __restrict__ src, unsigned short* __restrict__ dst, int n8) {
    int i = blockIdx.x*256 + threadIdx.x;
    if (i >= n8) return;
    const float* s = src + (size_t)i*8;
    f32x4 v0 = *(const f32x4*)s;
    f32x4 v1 = *(const f32x4*)(s + 4);
    bf16x8 o;
    o[0]=(short)f2bf(v0[0]); o[1]=(short)f2bf(v0[1]);
    o[2]=(short)f2bf(v0[2]); o[3]=(short)f2bf(v0[3]);
    o[4]=(short)f2bf(v1[0]); o[5]=(short)f2bf(v1[1]);
    o[6]=(short)f2bf(v1[2]); o[7]=(short)f2bf(v1[3]);
    *(bf16x8*)(dst + (size_t)i*8) = o;
}

// Wq_eff = (0.125*log2e*QSCALE)*(in_w[:E] @ qp_w); Wo_eff = outp_w @ op_w; bo_eff
__global__ void prep_eff_kernel(const float* __restrict__ in_w, const float* __restrict__ qp_w,
                                const float* __restrict__ outp_w, const float* __restrict__ op_w,
                                const float* __restrict__ op_b, const float* __restrict__ outp_b,
                                unsigned short* __restrict__ wq, unsigned short* __restrict__ wo,
                                float* __restrict__ bo) {
    int tid = blockIdx.x*256 + threadIdx.x;
    if (tid < 65536) {
        int n = tid >> 7, k = tid & 127;
        float s = 0.f;
        for (int e = 0; e < 512; ++e) s += in_w[(size_t)n*512 + e] * qp_w[(size_t)e*128 + k];
        wq[(size_t)n*128 + k] = f2bf(s * (0.125f * LOG2E * QSCALE));
    } else if (tid < 131072) {
        int t2 = tid - 65536; int n = t2 >> 9, k = t2 & 511;
        float s = 0.f;
        for (int e = 0; e < 512; ++e) s += outp_w[(size_t)n*512 + e] * op_w[(size_t)e*512 + k];
        wo[(size_t)n*512 + k] = f2bf(s);
    } else if (tid < 131200) {
        int n = tid - 131072;
        float s = outp_b[n];
        for (int e = 0; e < 512; ++e) s += outp_w[(size_t)n*512 + e] * op_b[e];
        bo[n] = s;
    }
}

__global__ void temb_kernel(const float* __restrict__ t1_w, const float* __restrict__ t1_b,
                            const float* __restrict__ t2_w, const float* __restrict__ t2_b,
                            float* __restrict__ temb) {
    int tid = blockIdx.x*256 + threadIdx.x;
    if (tid >= NSTEPS*512) return;
    int s = tid >> 9, e = tid & 511;
    float t = 1.0f - 0.05f * (float)s;
    float acc = t2_b[e];
    for (int i = 0; i < 512; ++i)
        acc += t2_w[(size_t)e*512 + i] * fmaxf(t * t1_w[i] + t1_b[i], 0.f);
    temb[tid] = acc;
}

__global__ void qbias_kernel(const float* __restrict__ in_w, const float* __restrict__ in_b,
                             const float* __restrict__ qp_b, const float* __restrict__ temb,
                             float* __restrict__ qbias) {
    int tid = blockIdx.x*256 + threadIdx.x;
    if (tid >= NSTEPS*512) return;
    int s = tid >> 9, n = tid & 511;
    float acc = in_b[n];
    const float* te = temb + (size_t)s*512;
    for (int e = 0; e < 512; ++e)
        acc += in_w[(size_t)n*512 + e] * (qp_b[e] + te[e]);
    qbias[tid] = acc * (0.125f * LOG2E * QSCALE);
}

// ---------------- fused K+V projection GEMM -> fp8 K/V (unchanged) --------
__global__ __launch_bounds__(512, 8) void kv_kernel(const unsigned short* __restrict__ condb,
                                                    const unsigned short* __restrict__ wkv,
                                                    const float* __restrict__ bias,
                                                    unsigned char* __restrict__ K8,
                                                    unsigned char* __restrict__ V8) {
    __shared__ unsigned short As[128*64];
    __shared__ unsigned short Bs[128*64];
    int tid = threadIdx.x;
    int blk = blockIdx.x;
    int xcd = blk & 7, j = blk >> 3;
    int m0 = (xcd*32 + (j >> 3)) * 128;
    int n0 = (j & 7) * 128;
    int wv = tid >> 6, lane = tid & 63, r = lane & 15, q = lane >> 4;
    int srow = lane >> 3;
    int sg = (lane & 7) ^ srow;
    const unsigned short* agl = condb + (size_t)(m0 + wv*16 + srow)*512 + sg*8;
    const unsigned short* bgl = wkv   + (size_t)(n0 + wv*16 + srow)*512 + sg*8;
    f32x4 acc[8] = {};
#pragma unroll
    for (int kt = 0; kt < 8; ++kt) {
        int k0 = kt * 64;
#pragma unroll
        for (int ii = 0; ii < 2; ++ii) {
            async_copy16(agl + (size_t)(ii*8)*512 + k0, &As[(wv*16 + ii*8)*64]);
            async_copy16(bgl + (size_t)(ii*8)*512 + k0, &Bs[(wv*16 + ii*8)*64]);
        }
        __syncthreads();
#pragma unroll
        for (int kk = 0; kk < 2; ++kk) {
            int gof = ((kk*4 + q) ^ (r & 7)) * 8;
            bf16x8 a = *(const bf16x8*)&As[(wv*16 + r)*64 + gof];
#pragma unroll
            for (int t = 0; t < 8; ++t) {
                bf16x8 b = *(const bf16x8*)&Bs[(t*16 + r)*64 + gof];
                acc[t] = MFMA(a, b, acc[t]);
            }
        }
        __syncthreads();
    }
    int mbase = m0 + wv*16 + q*4;
    int bb = mbase >> 8, kpb = mbase & 255;
#pragma unroll
    for (int t = 0; t < 8; ++t) {
        int n = n0 + t*16 + r;
        float bs = bias[n];
        if (n < 512) {
            int h = n >> 6, d = n & 63;
            int colp = ((d>>3)&3)*16 + ((d>>5)&1)*8 + (d&7);
            unsigned char* kp = K8 + (size_t)(bb*HH + h)*16384 + colp;
#pragma unroll
            for (int i = 0; i < 4; ++i)
                kp[(kpb + i)*64] = f2f8(acc[t][i] + bs);
        } else {
            int n2 = n - 512, h = n2 >> 6, d = n2 & 63;
            int kk = kpb >> 5, qq = (kpb >> 3) & 3, jb = kpb & 7;
            int colv = (kk>>1)*64 + qq*16 + (kk&1)*8 + jb;
            u32 w01 = __builtin_amdgcn_cvt_pk_fp8_f32(acc[t][0]+bs, acc[t][1]+bs, 0, false);
            w01 = __builtin_amdgcn_cvt_pk_fp8_f32(acc[t][2]+bs, acc[t][3]+bs, w01, true);
            *(u32*)(V8 + (size_t)(bb*HH + h)*16384 + d*256 + colv) = w01;
        }
    }
}

// ---------------- mega kernel: all 20 steps --------------------------------
// 512 blocks (2/CU) x 4 waves x 16 ROWS each. Rationale from r8/r9 counters:
// r8 (spill-free, 1 wave/SIMD) = 990us with MfmaUtil 8% and ~75% stall;
// r9 (2 waves/SIMD, spilled 123MB) = 1036us. This config targets BOTH:
// halved per-block rows halve the per-wave live set (~70 arch + ~50 agpr,
// half of r9's demand at the same 256-unified/wave budget) -> spill-free
// with slack, AND the two co-resident blocks per CU are barrier-independent
// so their phases slide (one block's latency-bound Phase A overlaps the
// other's MFMA-bound FFN on the same SIMDs).
// Phase A: wave = 2 heads sequential, 1 q-tile, flash over 4 key-quarters
// (r9's verified per-tile numerics). Phase B/FFN: wave = 32-col group.
__global__ __launch_bounds__(256, 2) void mega_kernel(
        const unsigned char* __restrict__ Kg,    // [b*8+h][256][64] fp8, col-permuted
        const unsigned char* __restrict__ Vg,    // [b*8+h][64][256] fp8, col-permuted
        const float* __restrict__ noise,
        const unsigned short* __restrict__ wq,   // [512][128] bf16 (x64*log2e scale)
        const float* __restrict__ qbiasB,        // [20][512]
        const unsigned short* __restrict__ wo,   // [128][512]
        const float* __restrict__ bo,
        const float* __restrict__ ln_g, const float* __restrict__ ln_b,
        const unsigned short* __restrict__ f1w,  // [512][128]
        const float* __restrict__ f1_b,
        const unsigned short* __restrict__ f2w,  // [128][512]
        const float* __restrict__ f2_b,
        float* __restrict__ outp) {
    __shared__ unsigned short xS[16*136];     // 4.4 KB
    __shared__ unsigned short cuS[16*520];    // 16.6 KB: ctx, then full-width u
    __shared__ unsigned short hnS[16*136];    // 4.4 KB
    __shared__ float redS[16*4], redS2[16*4];

    int tid = threadIdx.x, w = tid >> 6, lane = tid & 63, r = lane & 15, q = lane >> 4;
    // 512 blocks: 4 consecutive 16-row groups of one b land on one XCD
    int vblk = ((blockIdx.x & 7) << 6) | (blockIdx.x >> 3);
    int b = vblk >> 2;
    int row0 = vblk * 16;
    int srcA = r + ((2*q) & 3)*16;
    int srcB = r + ((2*q + 1) & 3)*16;
    int odd = (q >> 1) & 1;

    // x state: row q*4+i, col w*32+t*16+r
    float xf[2][4];
#pragma unroll
    for (int t = 0; t < 2; ++t)
#pragma unroll
        for (int i = 0; i < 4; ++i) {
            int rl = q*4 + i, col = w*32 + t*16 + r;
            float v = noise[(size_t)(row0 + rl)*AA + col];
            xf[t][i] = v;
            xS[rl*136 + col] = f2bf(v);
        }
    __syncthreads();

    const float dt = -1.f / (float)NSTEPS;

#pragma unroll 1
    for (int s = 0; s < NSTEPS; ++s) {
        const float* qb_s = qbiasB + (size_t)s*512;

        // ===== Phase A: 2 heads per wave sequential, flash 4 key-quarters ====
#pragma unroll 1
        for (int hp = 0; hp < 2; ++hp) {
            int h = w*2 + hp;
            const unsigned char* kbase = Kg + ((size_t)b*HH + h)*16384;
            const unsigned char* vbase = Vg + ((size_t)b*HH + h)*16384;

            // Q-proj (bf16): a = wq rows (L2-hot), b = x rows (LDS)
            f32x4 qacc[4] = {};
#pragma unroll
            for (int kk = 0; kk < 4; ++kk) {
                bf16x8 bx = *(const bf16x8*)&xS[(r)*136 + kk*32 + q*8];
#pragma unroll
                for (int t = 0; t < 4; ++t) {
                    bf16x8 a = *(const bf16x8*)(wq + (size_t)(h*HD + t*16 + r)*AA + kk*32 + q*8);
                    qacc[t] = MFMA(a, bx, qacc[t]);
                }
            }
            u32 qp[4];
#pragma unroll
            for (int t = 0; t < 4; ++t) {
                f32x4 qb4 = *(const f32x4*)(qb_s + h*HD + t*16 + q*4);
                f32x4 v;
#pragma unroll
                for (int i = 0; i < 4; ++i) v[i] = qacc[t][i] + qb4[i];
                qp[t] = pk4f8(v);
            }
            F8 bq[2];
            bq[0] = build8(qp, 0, srcA, srcB, odd);
            bq[1] = build8(qp, 1, srcA, srcB, odd);

            // flash state: running max (scaled units) + running sum
            float mr = -3e38f, l = 0.f;
            f32x4 c[4] = {};

#pragma unroll
            for (int qq = 0; qq < 4; ++qq) {
                // K prefetch for this quarter (4 x 16B)
                uint4 kbuf[4];
#pragma unroll
                for (int t = 0; t < 4; ++t)
                    kbuf[t] = *(const uint4*)(kbase + (size_t)((qq*4 + t)*16 + r)*64 + q*16);

                // S^T fp8 for this quarter
                f32x4 s0[4] = {};
#pragma unroll
                for (int t = 0; t < 4; ++t) {
                    F8 k0, k1;
                    k0.u[0] = kbuf[t].x; k0.u[1] = kbuf[t].y;
                    k1.u[0] = kbuf[t].z; k1.u[1] = kbuf[t].w;
                    s0[t] = MFMA8(k0.l, bq[0].l, s0[t]);
                    s0[t] = MFMA8(k1.l, bq[1].l, s0[t]);
                }

                // V prefetch for this quarter (independent of softmax VALU)
                uint4 vbuf[4];
#pragma unroll
                for (int t = 0; t < 4; ++t)
                    vbuf[t] = *(const uint4*)(vbase + (size_t)(t*16 + r)*256 + qq*64 + q*16);

                // quarter max (4-way split chains)
                float a0 = s0[0][0], a1 = s0[0][1], a2 = s0[0][2], a3 = s0[0][3];
#pragma unroll
                for (int t = 1; t < 4; ++t) {
                    a0 = fmaxf(a0, s0[t][0]); a1 = fmaxf(a1, s0[t][1]);
                    a2 = fmaxf(a2, s0[t][2]); a3 = fmaxf(a3, s0[t][3]);
                }
                float hm = fmaxf(fmaxf(a0, a1), fmaxf(a2, a3));
                hm = fmaxf(hm, __shfl_xor(hm, 16));
                hm = fmaxf(hm, __shfl_xor(hm, 32));
                float nm = fmaxf(mr, hm * INV_QS);
                float rs = exp2f(mr - nm);   // <=1; 0 on first quarter
                mr = nm;

                // exp + sum + pack (no writeback into s0)
                u32 pp[4];
                float t00 = 0.f, t01 = 0.f;
#pragma unroll
                for (int t = 0; t < 4; ++t) {
                    float e0 = exp2f(fmaf(s0[t][0], INV_QS, -nm));
                    float e1 = exp2f(fmaf(s0[t][1], INV_QS, -nm));
                    float e2 = exp2f(fmaf(s0[t][2], INV_QS, -nm));
                    float e3 = exp2f(fmaf(s0[t][3], INV_QS, -nm));
                    t00 += e0 + e2; t01 += e1 + e3;
                    f32x4 w0; w0[0]=e0*QSCALE; w0[1]=e1*QSCALE; w0[2]=e2*QSCALE; w0[3]=e3*QSCALE;
                    pp[t] = pk4f8(w0);
                }
                l = l * rs + (t00 + t01);

                // rescale ctx accumulators by row-redistributed factors
                float rr[4];
#pragma unroll
                for (int i = 0; i < 4; ++i) rr[i] = __shfl(rs, q*4 + i);
#pragma unroll
                for (int t = 0; t < 4; ++t)
#pragma unroll
                    for (int i = 0; i < 4; ++i) c[t][i] *= rr[i];

                // PV fp8 for this quarter (one 64-key group)
                {
                    F8 a0f = build8(pp, 0, srcA, srcB, odd);
                    F8 a1f = build8(pp, 1, srcA, srcB, odd);
#pragma unroll
                    for (int t = 0; t < 4; ++t) {
                        F8 v0, v1;
                        v0.u[0] = vbuf[t].x; v0.u[1] = vbuf[t].y;
                        v1.u[0] = vbuf[t].z; v1.u[1] = vbuf[t].w;
                        c[t] = MFMA8(a0f.l, v0.l, c[t]);
                        c[t] = MFMA8(a1f.l, v1.l, c[t]);
                    }
                }
            }

            // final normalization: reduce l across the 4 lane-groups
            l += __shfl_xor(l, 16); l += __shfl_xor(l, 32);
            float iv = 1.0f / l;
            float sc[4];
#pragma unroll
            for (int i = 0; i < 4; ++i) sc[i] = INV_QS * __shfl(iv, q*4 + i);
#pragma unroll
            for (int t = 0; t < 4; ++t)
#pragma unroll
                for (int i = 0; i < 4; ++i)
                    cuS[(q*4 + i)*520 + h*HD + t*16 + r] = f2bf(c[t][i] * sc[i]);
        }
        __syncthreads();   // ctx complete

        // ===== Phase B: out-proj + residual + LayerNorm (wave = col group) ==
        f32x4 oacc[2] = {};
#pragma unroll
        for (int kk = 0; kk < 16; ++kk) {
            bf16x8 a = *(const bf16x8*)&cuS[(r)*520 + kk*32 + q*8];
#pragma unroll
            for (int t = 0; t < 2; ++t) {
                bf16x8 bw = *(const bf16x8*)(wo + (size_t)(w*32 + t*16 + r)*EE + kk*32 + q*8);
                oacc[t] = MFMA(a, bw, oacc[t]);
            }
        }
        float hv[2][4];
#pragma unroll
        for (int t = 0; t < 2; ++t) {
            float bov = bo[w*32 + t*16 + r];
#pragma unroll
            for (int i = 0; i < 4; ++i) hv[t][i] = oacc[t][i] + bov + xf[t][i];
        }
#pragma unroll
        for (int i = 0; i < 4; ++i) {
            float s1 = hv[0][i] + hv[1][i];
            float s2 = hv[0][i]*hv[0][i] + hv[1][i]*hv[1][i];
            s1 += __shfl_xor(s1, 1);  s2 += __shfl_xor(s2, 1);
            s1 += __shfl_xor(s1, 2);  s2 += __shfl_xor(s2, 2);
            s1 += __shfl_xor(s1, 4);  s2 += __shfl_xor(s2, 4);
            s1 += __shfl_xor(s1, 8);  s2 += __shfl_xor(s2, 8);
            if (r == 0) { redS[(q*4 + i)*4 + w] = s1; redS2[(q*4 + i)*4 + w] = s2; }
        }
        __syncthreads();   // also: all ctx reads from cuS are done after this
        float hnv[2][4];
#pragma unroll
        for (int i = 0; i < 4; ++i) {
            int row = q*4 + i;
            float s1 = redS [row*4+0] + redS [row*4+1] + redS [row*4+2] + redS [row*4+3];
            float s2 = redS2[row*4+0] + redS2[row*4+1] + redS2[row*4+2] + redS2[row*4+3];
            float mu = s1 * (1.f/128.f);
            float var = s2 * (1.f/128.f) - mu*mu;
            float rstd = rsqrtf(var + 1e-5f);
#pragma unroll
            for (int t = 0; t < 2; ++t) {
                int col = w*32 + t*16 + r;
                float v = (hv[t][i] - mu) * rstd * ln_g[col] + ln_b[col];
                hnv[t][i] = v;
                hnS[row*136 + col] = f2bf(v);
            }
        }
        __syncthreads();

        // ===== FFN: full-width u into cuS, single barrier =====
        f32x4 o2[2] = {};
#pragma unroll 1
        for (int nt = 0; nt < 4; ++nt) {
            f32x4 a1[2] = {};
#pragma unroll
            for (int kk = 0; kk < 4; ++kk) {
                bf16x8 a = *(const bf16x8*)&hnS[(r)*136 + kk*32 + q*8];
#pragma unroll
                for (int t = 0; t < 2; ++t) {
                    bf16x8 bw = *(const bf16x8*)(f1w + (size_t)(nt*128 + w*32 + t*16 + r)*AA + kk*32 + q*8);
                    a1[t] = MFMA(a, bw, a1[t]);
                }
            }
#pragma unroll
            for (int t = 0; t < 2; ++t) {
                float b1 = f1_b[nt*128 + w*32 + t*16 + r];
#pragma unroll
                for (int i = 0; i < 4; ++i)
                    cuS[(q*4 + i)*520 + nt*128 + w*32 + t*16 + r] = f2bf(fmaxf(a1[t][i] + b1, 0.f));
            }
        }
        __syncthreads();   // all of u visible to all waves
#pragma unroll 1
        for (int nt = 0; nt < 4; ++nt) {
#pragma unroll
            for (int kk = 0; kk < 4; ++kk) {
                bf16x8 a = *(const bf16x8*)&cuS[(r)*520 + nt*128 + kk*32 + q*8];
#pragma unroll
                for (int t = 0; t < 2; ++t) {
                    bf16x8 bw = *(const bf16x8*)(f2w + (size_t)(w*32 + t*16 + r)*EE + nt*128 + kk*32 + q*8);
                    o2[t] = MFMA(a, bw, o2[t]);
                }
            }
        }

        // ===== x update =====
        if (s < NSTEPS - 1) {
#pragma unroll
            for (int t = 0; t < 2; ++t) {
                float b2 = f2_b[w*32 + t*16 + r];
#pragma unroll
                for (int i = 0; i < 4; ++i) {
                    float outv = hnv[t][i] + o2[t][i] + b2;
                    float xn = xf[t][i] + dt * outv;
                    xf[t][i] = xn;
                    xS[(q*4 + i)*136 + w*32 + t*16 + r] = f2bf(xn);
                }
            }
            __syncthreads();   // xS ready; cuS (u) reads done -> reusable as ctx
        } else {
#pragma unroll
            for (int t = 0; t < 2; ++t) {
                float b2 = f2_b[w*32 + t*16 + r];
#pragma unroll
                for (int i = 0; i < 4; ++i) {
                    float outv = hnv[t][i] + o2[t][i] + b2;
                    outp[(size_t)(row0 + q*4 + i)*AA + w*32 + t*16 + r] = xf[t][i] + dt * outv;
                }
            }
        }
    }
}

extern "C" void kernel_launch(void* const* d_in, const int* in_sizes, int n_in,
                              void* d_out, int out_size, void* d_ws, size_t ws_size,
                              hipStream_t stream) {
    const float* cond   = (const float*)d_in[0];
    const float* noise  = (const float*)d_in[1];
    const float* t1_w   = (const float*)d_in[2];
    const float* t1_b   = (const float*)d_in[3];
    const float* t2_w   = (const float*)d_in[4];
    const float* t2_b   = (const float*)d_in[5];
    const float* qp_w   = (const float*)d_in[6];
    const float* qp_b   = (const float*)d_in[7];
    const float* in_w   = (const float*)d_in[8];
    const float* in_b   = (const float*)d_in[9];
    const float* op_w   = (const float*)d_in[10];
    const float* op_b   = (const float*)d_in[11];
    const float* outp_w = (const float*)d_in[12];
    const float* outp_b = (const float*)d_in[13];
    const float* f1_w   = (const float*)d_in[14];
    const float* f1_b   = (const float*)d_in[15];
    const float* f2_w   = (const float*)d_in[16];
    const float* f2_b   = (const float*)d_in[17];
    const float* ln_g   = (const float*)d_in[18];
    const float* ln_bp  = (const float*)d_in[19];

    char* w = (char*)d_ws;
    auto alloc = [&](size_t bytes) {
        char* p = w;
        w += (bytes + 255) & ~(size_t)255;
        return p;
    };
    unsigned char*  K8     = (unsigned char*)alloc((size_t)NB*HH*CL*HD);      // 16.8 MB fp8
    unsigned char*  V8     = (unsigned char*)alloc((size_t)NB*HH*HD*CL);      // 16.8 MB fp8
    unsigned short* condb  = (unsigned short*)alloc((size_t)NB*CL*EE*2);      // 33.5 MB
    unsigned short* wkv_bf = (unsigned short*)alloc((size_t)1024*512*2);      // 1 MB
    unsigned short* wq_bf  = (unsigned short*)alloc((size_t)512*128*2);
    unsigned short* wo_bf  = (unsigned short*)alloc((size_t)128*512*2);
    unsigned short* f1_bf  = (unsigned short*)alloc((size_t)512*128*2);
    unsigned short* f2_bf  = (unsigned short*)alloc((size_t)128*512*2);
    float*          bo_eff = (float*)alloc(128*4);
    float*          tembB  = (float*)alloc((size_t)NSTEPS*512*4);
    float*          qbiasB = (float*)alloc((size_t)NSTEPS*512*4);
    (void)ws_size; (void)n_in; (void)in_sizes; (void)out_size;

    // --- one-time prep ---
    cvt8_kernel<<<8192, 256, 0, stream>>>(cond, condb, NB*CL*EE/8);
    cvt8_kernel<<<256, 256, 0, stream>>>(in_w + 512*512, wkv_bf, 1024*512/8);
    cvt8_kernel<<<32, 256, 0, stream>>>(f1_w, f1_bf, 512*128/8);
    cvt8_kernel<<<32, 256, 0, stream>>>(f2_w, f2_bf, 128*512/8);
    prep_eff_kernel<<<513, 256, 0, stream>>>(in_w, qp_w, outp_w, op_w, op_b, outp_b,
                                             wq_bf, wo_bf, bo_eff);
    temb_kernel<<<40, 256, 0, stream>>>(t1_w, t1_b, t2_w, t2_b, tembB);
    qbias_kernel<<<40, 256, 0, stream>>>(in_w, in_b, qp_b, tembB, qbiasB);
    kv_kernel<<<2048, 512, 0, stream>>>(condb, wkv_bf, in_b + 512, K8, V8);

    // --- all 20 denoise steps, one kernel, 512 blocks x 4 waves ---
    mega_kernel<<<512, 256, 0, stream>>>(K8, V8, noise, wq_bf, qbiasB,
                                         wo_bf, bo_eff, ln_g, ln_bp,
                                         f1_bf, f1_b, f2_bf, f2_b,
                                         (float*)d_out);
}